// Round 6
// baseline (470.675 us; speedup 1.0000x reference)
//
#include <hip/hip_runtime.h>
#include <math.h>

#define BB 64
#define TT 8192
#define NTILES 8192      // 524288 positions / 64 per tile
#define MLP_GRID 2048    // 4 tiles/block: base + i*2048, i=0..3 (guard-free)
#define EMA_GRID 512     // 64 b * 8 chunks of 1024 t

typedef short short8 __attribute__((ext_vector_type(8)));
typedef float f32x4 __attribute__((ext_vector_type(4)));

// f32 -> bf16 bits, RNE
__device__ __forceinline__ unsigned short f2bf(float x) {
    unsigned int u = __float_as_uint(x);
    u += 0x7fffu + ((u >> 16) & 1u);
    return (unsigned short)(u >> 16);
}

// two f32 -> packed bf16x2 (lo | hi<<16)
__device__ __forceinline__ unsigned int f2bf2(float lo, float hi) {
    return (unsigned int)f2bf(lo) | ((unsigned int)f2bf(hi) << 16);
}

__device__ __forceinline__ float fast_sigmoid(float z) {
    return __builtin_amdgcn_rcpf(1.0f + __expf(-z));
}

__device__ __forceinline__ float fast_gelu(float x) {
    // x * sigmoid(1.702x); abs err ~0.02 vs erf-gelu, budget is 2.1e4
    return x * fast_sigmoid(1.702f * x);
}

// ---------------------------------------------------------------------------
// EMA kernel (unchanged -- verified)
// ---------------------------------------------------------------------------
__global__ __launch_bounds__(256) void ema_kernel(
    const float* __restrict__ gaze, const float* __restrict__ logthr,
    const float* __restrict__ invT, float* __restrict__ qf, float* __restrict__ qs)
{
    __shared__ __align__(16) float sg[1280];
    const int tid = threadIdx.x;
    const int b   = blockIdx.x >> 3;
    const int t0  = (blockIdx.x & 7) << 10;
    const float thr = __expf(logthr[0]);
    const float sT  = invT[0];
    const float2* gz = (const float2*)gaze + (size_t)b * TT;

    #pragma unroll
    for (int it = 0; it < 5; ++it) {
        int i = tid + it * 256;
        int t = t0 - 252 + i;
        float val = 0.0f;
        if (t >= 0 && t < TT) {
            float vx = 0.0f, vy = 0.0f;
            if (t > 0) {
                float2 a = gz[t], p = gz[t - 1];
                vx = (a.x - p.x) * 240.0f;
                vy = (a.y - p.y) * 240.0f;
            }
            float speed = sqrtf(vx * vx + vy * vy);
            val = 1.0f / (1.0f + __expf(-sT * (speed - thr)));
        }
        sg[i] = val;
    }
    __syncthreads();

    const float4* sg4 = (const float4*)sg;
    float Sf = 0.0f, Ss = 0.0f;
    float wf = 0.16f;       // 0.2 * 0.8
    float ws = 0.0475f;     // 0.05 * 0.95
    for (int u = 62; u >= 0; --u) {
        float4 qv = sg4[tid + u];
        float hf = fmaf(0.8f,  fmaf(0.8f,  fmaf(0.8f,  qv.x, qv.y), qv.z), qv.w);
        Sf = fmaf(wf, hf, Sf);  wf *= 0.4096f;
        float hs = fmaf(0.95f, fmaf(0.95f, fmaf(0.95f, qv.x, qv.y), qv.z), qv.w);
        Ss = fmaf(ws, hs, Ss);  ws *= 0.81450625f;
    }
    float4 r = sg4[tid + 63];
    float g0v = r.x, g1v = r.y, g2v = r.z, g3v = r.w;

    float o0 = Sf + 0.2f * g0v;
    float o1 = fmaf(0.8f,   Sf, 0.2f * fmaf(0.8f, g0v, g1v));
    float o2 = fmaf(0.64f,  Sf, 0.2f * (g2v + 0.8f * g1v + 0.64f * g0v));
    float o3 = fmaf(0.512f, Sf, 0.2f * (g3v + 0.8f * g2v + 0.64f * g1v + 0.512f * g0v));

    float p0 = Ss + 0.05f * g0v;
    float p1 = fmaf(0.95f,     Ss, 0.05f * fmaf(0.95f, g0v, g1v));
    float p2 = fmaf(0.9025f,   Ss, 0.05f * (g2v + 0.95f * g1v + 0.9025f * g0v));
    float p3 = fmaf(0.857375f, Ss, 0.05f * (g3v + 0.95f * g2v + 0.9025f * g1v + 0.857375f * g0v));

    const size_t ob = (size_t)b * TT + t0 + 4 * tid;
    *(float4*)(qf + ob) = make_float4(o0, o1, o2, o3);
    *(float4*)(qs + ob) = make_float4(p0, p1, p2, p3);
}

// ---------------------------------------------------------------------------
// MLP kernel, depth-2 software pipeline. vs r5 (310.8us):
//  - body split into front (loads+features+L1-MFMA+repack -> 4 A2 frags)
//    and back (L2 LDS reads + MFMA + cached stores). Schedule per block:
//    f0; f1; back0; f2; back1; f3; back2; back3 -- front(i+1)'s global loads
//    and trans-heavy VALU overlap back(i)'s LDS/MFMA/store phase (r3 showed
//    exposed latency converts ~1:1 into time at this occupancy).
//  - feature branches made branchless (selects): all q-paths issued serially
//    under exec-masking anyway; single BB lets the scheduler interleave.
//  - launch_bounds(256,3): frag-in-flight (+16 regs) makes a 128-VGPR cap
//    spill (r2 lesson); 12 waves/CU x 2-deep ILP > 16 x 1-deep.
//  - sigma-permuted channels, sW2 LDS, cached stores: identical to r5.
// ---------------------------------------------------------------------------
struct Frags { short8 a[4]; };
struct B1s   { short8 b[8]; };

__device__ __forceinline__ Frags mlp_front(
    int tile, int wave, int c, int q,
    const float2* __restrict__ gz, const float* __restrict__ qf,
    const float* __restrict__ qs, const B1s& B1,
    float cwx0, float cwx1, float cwy0, float cwy1,
    float px0, float px1, float py0, float py1,
    float thr, float sT)
{
    const int b   = tile >> 7;
    const int t0  = (tile & 127) << 6;
    const int t   = t0 + wave * 16 + c;
    const int idx = b * TT + t;

    float2 g0 = gz[idx];
    float2 g1 = (t > 0) ? gz[idx - 1] : g0;
    float2 g2 = (t > 1) ? gz[idx - 2] : g1;
    float qfv = qf[idx];
    float qsv = qs[idx];

    float vx = (g0.x - g1.x) * 240.0f;
    float vy = (g0.y - g1.y) * 240.0f;
    float vpx = (g1.x - g2.x) * 240.0f;
    float vpy = (g1.y - g2.y) * 240.0f;
    float ax = (vx - vpx) * 240.0f;
    float ay = (vy - vpy) * 240.0f;
    float speed  = sqrtf(vx * vx + vy * vy);
    float inv_sp = __builtin_amdgcn_rcpf(speed + 1e-6f);

    float s0, c0s, s1, c1s, s2, c2s, s3, c3s;
    __sincosf(fmaf(g0.x, cwx0, px0), &s0, &c0s);
    __sincosf(fmaf(g0.x, cwx1, px1), &s1, &c1s);
    __sincosf(fmaf(g0.y, cwy0, py0), &s2, &c2s);
    __sincosf(fmaf(g0.y, cwy1, py1), &s3, &c3s);
    float gate = fast_sigmoid(sT * (speed - thr));

    const bool q0 = (q == 0), q1 = (q == 1), q2 = (q == 2);
    float f[8];
    f[0] = q0 ? s0  : (q1 ? vx            : (q2 ? (vx * ay - vy * ax) * inv_sp : 0.f));
    f[1] = q0 ? s1  : (q1 ? vy            : (q2 ? gate : 0.f));
    f[2] = q0 ? c0s : (q1 ? speed         : (q2 ? qfv  : 0.f));
    f[3] = q0 ? c1s : (q1 ? vx * inv_sp   : (q2 ? qsv  : 0.f));
    f[4] = q0 ? s2  : (q1 ? vy * inv_sp   : (q2 ? 1.0f : 0.f));   // k=20: b1 carrier
    f[5] = q0 ? s3  : (q1 ? ax            : 0.f);
    f[6] = q0 ? c2s : (q1 ? ay            : 0.f);
    f[7] = q0 ? c3s : (q1 ? (vx * ax + vy * ay) * inv_sp : 0.f);

    union { unsigned short u[8]; short8 v; } A1;
    #pragma unroll
    for (int k = 0; k < 8; ++k) A1.u[k] = f2bf(f[k]);

    // layer 1: 8 MFMAs, accumulators in registers (sigma-permuted channels)
    f32x4 acc1[8];
    #pragma unroll
    for (int j = 0; j < 8; ++j) {
        f32x4 z = {0.f, 0.f, 0.f, 0.f};
        acc1[j] = __builtin_amdgcn_mfma_f32_16x16x32_bf16(B1.b[j], A1.v, z, 0, 0, 0);
    }

    // lane-local repack: A2[s] = channels {32s+8q+u}, pos=c
    Frags r;
    #pragma unroll
    for (int s = 0; s < 4; ++s) {
        union { unsigned int w[4]; short8 v; } t2;
        t2.w[0] = f2bf2(fast_gelu(acc1[s][0]),     fast_gelu(acc1[s][1]));
        t2.w[1] = f2bf2(fast_gelu(acc1[s][2]),     fast_gelu(acc1[s][3]));
        t2.w[2] = f2bf2(fast_gelu(acc1[s + 4][0]), fast_gelu(acc1[s + 4][1]));
        t2.w[3] = f2bf2(fast_gelu(acc1[s + 4][2]), fast_gelu(acc1[s + 4][3]));
        r.a[s] = t2.v;
    }
    return r;
}

__device__ __forceinline__ void mlp_back(
    int tile, int wave, int c, int q, const Frags& A2,
    const unsigned short* sW2p, const float* sb2p, float* __restrict__ out)
{
    const int b  = tile >> 7;
    const int t0 = (tile & 127) << 6;
    float* ob = out + (size_t)(b * TT + t0 + wave * 16 + c) * 128 + 4 * q;
    #pragma unroll
    for (int j = 0; j < 8; ++j) {
        f32x4 acc = *(const f32x4*)&sb2p[16 * j + 4 * q];
        #pragma unroll
        for (int s = 0; s < 4; ++s) {
            short8 W2f = *(const short8*)&sW2p[(16 * j + c) * 136 + 32 * s + 8 * q];
            acc = __builtin_amdgcn_mfma_f32_16x16x32_bf16(W2f, A2.a[s], acc, 0, 0, 0);
        }
        f32x4 o;
        #pragma unroll
        for (int r = 0; r < 4; ++r) o[r] = fast_gelu(acc[r]);
        *(f32x4*)(ob + 16 * j) = o;   // cached store: L2 merges into full lines
    }
}

__global__ __launch_bounds__(256, 3) void mlp_kernel(
    const float* __restrict__ gaze,
    const float* __restrict__ lwx, const float* __restrict__ phx,
    const float* __restrict__ lwy, const float* __restrict__ phy,
    const float* __restrict__ logthr, const float* __restrict__ invT,
    const float* __restrict__ W1, const float* __restrict__ b1,
    const float* __restrict__ W2, const float* __restrict__ b2,
    const float* __restrict__ qf, const float* __restrict__ qs,
    float* __restrict__ out)
{
    // W2^T[n][k], bf16, row stride 136 (16B-aligned rows; <=2-way aliasing)
    __shared__ __align__(16) unsigned short sW2[128 * 136];     // 34816 B
    __shared__ __align__(16) float sb2[128];                    // 512 B

    const int tid  = threadIdx.x;
    const int lane = tid & 63;
    const int wave = tid >> 6;
    const int c    = lane & 15;
    const int q    = lane >> 4;

    // ---- stage W2^T bf16 (one-time; coalesced over n) ----
    #pragma unroll
    for (int it = 0; it < 32; ++it) {
        int i  = tid + it * 256;
        int n  = i & 127;
        int kp = i >> 7;
        unsigned short lo = f2bf(W2[(2 * kp) * 128 + n]);
        unsigned short hi = f2bf(W2[(2 * kp + 1) * 128 + n]);
        *(unsigned int*)&sW2[n * 136 + 2 * kp] = ((unsigned int)hi << 16) | lo;
    }
    if (tid < 128) sb2[tid] = b2[tid];

    // ---- W1^T frags, sigma-permuted rows: B1.b[j] lane (c,q) holds
    //      W1^T[ch=sigma(j,c)][k=8q..8q+7]; k==20 carries b1[ch] ----
    B1s B1;
    #pragma unroll
    for (int j = 0; j < 8; ++j) {
        const int ch = 32 * (j & 3) + 8 * (c >> 2) + 4 * (j >> 2) + (c & 3);
        union { unsigned short u[8]; short8 v; } tmp;
        #pragma unroll
        for (int u = 0; u < 8; ++u) {
            int k = 8 * q + u;
            float w = 0.0f;
            if (k < 20)       w = W1[k * 128 + ch];
            else if (k == 20) w = b1[ch];
            tmp.u[u] = (k <= 20) ? f2bf(w) : (unsigned short)0;
        }
        B1.b[j] = tmp.v;
    }

    const float twopi = 6.283185307179586f;
    const float cwx0 = twopi * __expf(lwx[0]), cwx1 = twopi * __expf(lwx[1]);
    const float cwy0 = twopi * __expf(lwy[0]), cwy1 = twopi * __expf(lwy[1]);
    const float px0 = phx[0], px1 = phx[1], py0 = phy[0], py1 = phy[1];
    const float thr = __expf(logthr[0]), sT = invT[0];

    __syncthreads();   // sW2/sb2 visible; no barriers needed after this

    const float2* gz = (const float2*)gaze;
    const int base = blockIdx.x;

    // depth-2 software pipeline over the block's 4 tiles
    Frags f0 = mlp_front(base,                wave, c, q, gz, qf, qs, B1,
                         cwx0, cwx1, cwy0, cwy1, px0, px1, py0, py1, thr, sT);
    Frags f1 = mlp_front(base +     MLP_GRID, wave, c, q, gz, qf, qs, B1,
                         cwx0, cwx1, cwy0, cwy1, px0, px1, py0, py1, thr, sT);
    mlp_back(base,                wave, c, q, f0, sW2, sb2, out);
    Frags f2 = mlp_front(base + 2 * MLP_GRID, wave, c, q, gz, qf, qs, B1,
                         cwx0, cwx1, cwy0, cwy1, px0, px1, py0, py1, thr, sT);
    mlp_back(base +     MLP_GRID, wave, c, q, f1, sW2, sb2, out);
    Frags f3 = mlp_front(base + 3 * MLP_GRID, wave, c, q, gz, qf, qs, B1,
                         cwx0, cwx1, cwy0, cwy1, px0, px1, py0, py1, thr, sT);
    mlp_back(base + 2 * MLP_GRID, wave, c, q, f2, sW2, sb2, out);
    mlp_back(base + 3 * MLP_GRID, wave, c, q, f3, sW2, sb2, out);
}

extern "C" void kernel_launch(void* const* d_in, const int* in_sizes, int n_in,
                              void* d_out, int out_size, void* d_ws, size_t ws_size,
                              hipStream_t stream)
{
    const float* gaze   = (const float*)d_in[0];
    const float* lwx    = (const float*)d_in[1];
    const float* phx    = (const float*)d_in[2];
    const float* lwy    = (const float*)d_in[3];
    const float* phy    = (const float*)d_in[4];
    const float* logthr = (const float*)d_in[5];
    const float* invT   = (const float*)d_in[6];
    const float* W1     = (const float*)d_in[7];
    const float* b1     = (const float*)d_in[8];
    const float* W2     = (const float*)d_in[9];
    const float* b2     = (const float*)d_in[10];
    float* out = (float*)d_out;

    float* qf = (float*)d_ws;            // 2 MB
    float* qs = qf + BB * TT;            // 2 MB (ws_size >= 4 MB)

    ema_kernel<<<EMA_GRID, 256, 0, stream>>>(gaze, logthr, invT, qf, qs);
    mlp_kernel<<<MLP_GRID, 256, 0, stream>>>(gaze, lwx, phx, lwy, phy, logthr, invT,
                                             W1, b1, W2, b2, qf, qs, out);
}

// Round 7
// 312.937 us; speedup vs baseline: 1.5041x; 1.5041x over previous
//
#include <hip/hip_runtime.h>
#include <math.h>

#define BB 64
#define TT 8192
#define NTILES 8192      // 524288 positions / 64 per tile
#define MLP_GRID 768     // 3 blocks/CU resident (LDS 53760*3 <= 160 KiB)
#define EMA_GRID 512     // 64 b * 8 chunks of 1024 t

typedef short short8 __attribute__((ext_vector_type(8)));
typedef float f32x4 __attribute__((ext_vector_type(4)));

// f32 -> bf16 bits, RNE
__device__ __forceinline__ unsigned short f2bf(float x) {
    unsigned int u = __float_as_uint(x);
    u += 0x7fffu + ((u >> 16) & 1u);
    return (unsigned short)(u >> 16);
}

// two f32 -> packed bf16x2 (lo | hi<<16)
__device__ __forceinline__ unsigned int f2bf2(float lo, float hi) {
    return (unsigned int)f2bf(lo) | ((unsigned int)f2bf(hi) << 16);
}

__device__ __forceinline__ float fast_sigmoid(float z) {
    return __builtin_amdgcn_rcpf(1.0f + __expf(-z));
}

__device__ __forceinline__ float fast_gelu(float x) {
    // x * sigmoid(1.702x); abs err ~0.02 vs erf-gelu, budget is 2.1e4
    return x * fast_sigmoid(1.702f * x);
}

// ---------------------------------------------------------------------------
// EMA kernel (unchanged -- verified)
// ---------------------------------------------------------------------------
__global__ __launch_bounds__(256) void ema_kernel(
    const float* __restrict__ gaze, const float* __restrict__ logthr,
    const float* __restrict__ invT, float* __restrict__ qf, float* __restrict__ qs)
{
    __shared__ __align__(16) float sg[1280];
    const int tid = threadIdx.x;
    const int b   = blockIdx.x >> 3;
    const int t0  = (blockIdx.x & 7) << 10;
    const float thr = __expf(logthr[0]);
    const float sT  = invT[0];
    const float2* gz = (const float2*)gaze + (size_t)b * TT;

    #pragma unroll
    for (int it = 0; it < 5; ++it) {
        int i = tid + it * 256;
        int t = t0 - 252 + i;
        float val = 0.0f;
        if (t >= 0 && t < TT) {
            float vx = 0.0f, vy = 0.0f;
            if (t > 0) {
                float2 a = gz[t], p = gz[t - 1];
                vx = (a.x - p.x) * 240.0f;
                vy = (a.y - p.y) * 240.0f;
            }
            float speed = sqrtf(vx * vx + vy * vy);
            val = 1.0f / (1.0f + __expf(-sT * (speed - thr)));
        }
        sg[i] = val;
    }
    __syncthreads();

    const float4* sg4 = (const float4*)sg;
    float Sf = 0.0f, Ss = 0.0f;
    float wf = 0.16f;       // 0.2 * 0.8
    float ws = 0.0475f;     // 0.05 * 0.95
    for (int u = 62; u >= 0; --u) {
        float4 qv = sg4[tid + u];
        float hf = fmaf(0.8f,  fmaf(0.8f,  fmaf(0.8f,  qv.x, qv.y), qv.z), qv.w);
        Sf = fmaf(wf, hf, Sf);  wf *= 0.4096f;
        float hs = fmaf(0.95f, fmaf(0.95f, fmaf(0.95f, qv.x, qv.y), qv.z), qv.w);
        Ss = fmaf(ws, hs, Ss);  ws *= 0.81450625f;
    }
    float4 r = sg4[tid + 63];
    float g0v = r.x, g1v = r.y, g2v = r.z, g3v = r.w;

    float o0 = Sf + 0.2f * g0v;
    float o1 = fmaf(0.8f,   Sf, 0.2f * fmaf(0.8f, g0v, g1v));
    float o2 = fmaf(0.64f,  Sf, 0.2f * (g2v + 0.8f * g1v + 0.64f * g0v));
    float o3 = fmaf(0.512f, Sf, 0.2f * (g3v + 0.8f * g2v + 0.64f * g1v + 0.512f * g0v));

    float p0 = Ss + 0.05f * g0v;
    float p1 = fmaf(0.95f,     Ss, 0.05f * fmaf(0.95f, g0v, g1v));
    float p2 = fmaf(0.9025f,   Ss, 0.05f * (g2v + 0.95f * g1v + 0.9025f * g0v));
    float p3 = fmaf(0.857375f, Ss, 0.05f * (g3v + 0.95f * g2v + 0.9025f * g1v + 0.857375f * g0v));

    const size_t ob = (size_t)b * TT + t0 + 4 * tid;
    *(float4*)(qf + ob) = make_float4(o0, o1, o2, o3);
    *(float4*)(qs + ob) = make_float4(p0, p1, p2, p3);
}

// ---------------------------------------------------------------------------
// MLP kernel = r5 body (310.8us) + contiguous-store epilogue. r6 counters
// showed FETCH_SIZE ~= output size: scattered 64B store chunks make L2 do
// read-for-ownership on every output line (~268 MB wasted HBM reads). The
// harness fill (contiguous stores) shows FETCH ~= 0 -> full-line-covering
// contiguous stores avoid RFO. So: per channel-half, stage the wave's
// 16pos x 64ch f32 outputs in LDS (stride 72 floats: write AND read
// bank-uniform at the b128 floor, hand-checked), then 4 x 1KB contiguous
// wave stores (each covers 8 full 128B lines). Wave-local lgkmcnt only,
// no barriers. LDS 34816+512+18432 = 53760 -> 3 blocks/CU; (256,3) so the
// +16 transient regs cannot spill (r2/r6 lesson). Grid 768 (3%% tail).
// Everything else identical to r5 (sigma-permuted channels, no h1
// roundtrip, cached stores).
// ---------------------------------------------------------------------------
__global__ __launch_bounds__(256, 3) void mlp_kernel(
    const float* __restrict__ gaze,
    const float* __restrict__ lwx, const float* __restrict__ phx,
    const float* __restrict__ lwy, const float* __restrict__ phy,
    const float* __restrict__ logthr, const float* __restrict__ invT,
    const float* __restrict__ W1, const float* __restrict__ b1,
    const float* __restrict__ W2, const float* __restrict__ b2,
    const float* __restrict__ qf, const float* __restrict__ qs,
    float* __restrict__ out)
{
    // W2^T[n][k], bf16, row stride 136 (16B-aligned rows; <=2-way aliasing)
    __shared__ __align__(16) unsigned short sW2[128 * 136];     // 34816 B
    __shared__ __align__(16) float sb2[128];                    // 512 B
    // per-wave output transpose area: [pos=16][64ch half, stride 72 floats]
    __shared__ __align__(16) float sO[4][16 * 72];              // 18432 B

    const int tid  = threadIdx.x;
    const int lane = tid & 63;
    const int wave = tid >> 6;
    const int c    = lane & 15;
    const int q    = lane >> 4;

    // ---- stage W2^T bf16 (one-time; coalesced over n) ----
    #pragma unroll
    for (int it = 0; it < 32; ++it) {
        int i  = tid + it * 256;
        int n  = i & 127;
        int kp = i >> 7;
        unsigned short lo = f2bf(W2[(2 * kp) * 128 + n]);
        unsigned short hi = f2bf(W2[(2 * kp + 1) * 128 + n]);
        *(unsigned int*)&sW2[n * 136 + 2 * kp] = ((unsigned int)hi << 16) | lo;
    }
    if (tid < 128) sb2[tid] = b2[tid];

    // ---- W1^T frags, sigma-permuted rows: B1[j] lane (c,q) holds
    //      W1^T[ch=sigma(j,c)][k=8q..8q+7]; k==20 carries b1[ch] ----
    short8 B1[8];
    #pragma unroll
    for (int j = 0; j < 8; ++j) {
        const int ch = 32 * (j & 3) + 8 * (c >> 2) + 4 * (j >> 2) + (c & 3);
        union { unsigned short u[8]; short8 v; } tmp;
        #pragma unroll
        for (int u = 0; u < 8; ++u) {
            int k = 8 * q + u;
            float w = 0.0f;
            if (k < 20)       w = W1[k * 128 + ch];
            else if (k == 20) w = b1[ch];
            tmp.u[u] = (k <= 20) ? f2bf(w) : (unsigned short)0;
        }
        B1[j] = tmp.v;
    }

    const float twopi = 6.283185307179586f;
    const float cwx0 = twopi * __expf(lwx[0]), cwx1 = twopi * __expf(lwx[1]);
    const float cwy0 = twopi * __expf(lwy[0]), cwy1 = twopi * __expf(lwy[1]);
    const float px0 = phx[0], px1 = phx[1], py0 = phy[0], py1 = phy[1];
    const float thr = __expf(logthr[0]), sT = invT[0];

    __syncthreads();   // sW2/sb2 visible; no barriers needed after this

    const float2* gz = (const float2*)gaze;
    float* so = sO[wave];

    for (int tile = blockIdx.x; tile < NTILES; tile += MLP_GRID) {
        const int b   = tile >> 7;
        const int t0  = (tile & 127) << 6;
        const int t   = t0 + wave * 16 + c;
        const int idx = b * TT + t;

        float2 g0 = gz[idx];
        float2 g1 = (t > 0) ? gz[idx - 1] : g0;
        float2 g2 = (t > 1) ? gz[idx - 2] : g1;
        float vx = (g0.x - g1.x) * 240.0f;
        float vy = (g0.y - g1.y) * 240.0f;
        float vpx = (g1.x - g2.x) * 240.0f;
        float vpy = (g1.y - g2.y) * 240.0f;
        float ax = (vx - vpx) * 240.0f;
        float ay = (vy - vpy) * 240.0f;
        float speed  = sqrtf(vx * vx + vy * vy);
        float inv_sp = __builtin_amdgcn_rcpf(speed + 1e-6f);

        float f[8] = {0.f, 0.f, 0.f, 0.f, 0.f, 0.f, 0.f, 0.f};
        if (q == 0) {
            __sincosf(fmaf(g0.x, cwx0, px0), &f[0], &f[2]);
            __sincosf(fmaf(g0.x, cwx1, px1), &f[1], &f[3]);
            __sincosf(fmaf(g0.y, cwy0, py0), &f[4], &f[6]);
            __sincosf(fmaf(g0.y, cwy1, py1), &f[5], &f[7]);
        } else if (q == 1) {
            f[0] = vx; f[1] = vy; f[2] = speed;
            f[3] = vx * inv_sp; f[4] = vy * inv_sp;
            f[5] = ax; f[6] = ay;
            f[7] = (vx * ax + vy * ay) * inv_sp;
        } else if (q == 2) {
            f[0] = (vx * ay - vy * ax) * inv_sp;
            f[1] = fast_sigmoid(sT * (speed - thr));
            f[2] = qf[idx];
            f[3] = qs[idx];
            f[4] = 1.0f;          // k=20: constant-1 feature carries b1
        } // q==3: zeros (K padding)

        union { unsigned short u[8]; short8 v; } A1;
        #pragma unroll
        for (int k = 0; k < 8; ++k) A1.u[k] = f2bf(f[k]);

        // ---- layer 1: 8 MFMAs, accumulators stay in registers ----
        f32x4 acc1[8];
        #pragma unroll
        for (int j = 0; j < 8; ++j) {
            f32x4 z = {0.f, 0.f, 0.f, 0.f};
            acc1[j] = __builtin_amdgcn_mfma_f32_16x16x32_bf16(B1[j], A1.v, z, 0, 0, 0);
        }

        // ---- lane-local repack: A2[s] = channels {32s+8q+u}, pos=c ----
        short8 A2[4];
        #pragma unroll
        for (int s = 0; s < 4; ++s) {
            union { unsigned int w[4]; short8 v; } t2;
            t2.w[0] = f2bf2(fast_gelu(acc1[s][0]),     fast_gelu(acc1[s][1]));
            t2.w[1] = f2bf2(fast_gelu(acc1[s][2]),     fast_gelu(acc1[s][3]));
            t2.w[2] = f2bf2(fast_gelu(acc1[s + 4][0]), fast_gelu(acc1[s + 4][1]));
            t2.w[3] = f2bf2(fast_gelu(acc1[s + 4][2]), fast_gelu(acc1[s + 4][3]));
            A2[s] = t2.v;
        }

        // ---- layer 2 + contiguous-store epilogue, per channel-half ----
        const size_t obase = (size_t)(b * TT + t0 + wave * 16) * 128;
        #pragma unroll
        for (int jh = 0; jh < 2; ++jh) {
            // compute 4 output blocks (channels 64*jh .. +63), stage to LDS
            #pragma unroll
            for (int jl = 0; jl < 4; ++jl) {
                const int j = 4 * jh + jl;
                f32x4 acc = *(const f32x4*)&sb2[16 * j + 4 * q];
                #pragma unroll
                for (int s = 0; s < 4; ++s) {
                    short8 W2f = *(const short8*)&sW2[(16 * j + c) * 136 + 32 * s + 8 * q];
                    acc = __builtin_amdgcn_mfma_f32_16x16x32_bf16(W2f, A2[s], acc, 0, 0, 0);
                }
                f32x4 o;
                #pragma unroll
                for (int r = 0; r < 4; ++r) o[r] = fast_gelu(acc[r]);
                // pos=c, half-local channel 16*jl+4q+r
                *(f32x4*)&so[c * 72 + 16 * jl + 4 * q] = o;
            }
            asm volatile("s_waitcnt lgkmcnt(0)" ::: "memory");  // wave-local RAW

            // 4 x 1KB contiguous wave stores: lane covers 16B chunk fch
            #pragma unroll
            for (int r = 0; r < 4; ++r) {
                const int fch = r * 64 + lane;   // chunk id in this half (0..255)
                const int pl  = fch >> 4;        // position 0..15
                const int c16 = fch & 15;        // 16B chunk within 256B half-row
                f32x4 v = *(const f32x4*)&so[pl * 72 + c16 * 4];
                *(f32x4*)(out + obase + (size_t)pl * 128 + jh * 64 + c16 * 4) = v;
            }
            asm volatile("s_waitcnt lgkmcnt(0)" ::: "memory");  // reads done before overwrite
        }
    }
}

extern "C" void kernel_launch(void* const* d_in, const int* in_sizes, int n_in,
                              void* d_out, int out_size, void* d_ws, size_t ws_size,
                              hipStream_t stream)
{
    const float* gaze   = (const float*)d_in[0];
    const float* lwx    = (const float*)d_in[1];
    const float* phx    = (const float*)d_in[2];
    const float* lwy    = (const float*)d_in[3];
    const float* phy    = (const float*)d_in[4];
    const float* logthr = (const float*)d_in[5];
    const float* invT   = (const float*)d_in[6];
    const float* W1     = (const float*)d_in[7];
    const float* b1     = (const float*)d_in[8];
    const float* W2     = (const float*)d_in[9];
    const float* b2     = (const float*)d_in[10];
    float* out = (float*)d_out;

    float* qf = (float*)d_ws;            // 2 MB
    float* qs = qf + BB * TT;            // 2 MB (ws_size >= 4 MB)

    ema_kernel<<<EMA_GRID, 256, 0, stream>>>(gaze, logthr, invT, qf, qs);
    mlp_kernel<<<MLP_GRID, 256, 0, stream>>>(gaze, lwx, phx, lwy, phy, logthr, invT,
                                             W1, b1, W2, b2, qf, qs, out);
}